// Round 16
// baseline (85.213 us; speedup 1.0000x reference)
//
#include <hip/hip_runtime.h>
#include <hip/hip_bf16.h>
#include <stdint.h>
#include <math.h>

// TernaryMobiusLinear: out = mobius( (x @ W) * scale ), x 8192x2048 fp32, W ternary.
// Path: x -> i8 per-row quant; W -> i8 exact; 32x32x32 i8 MFMA GEMM (i32 accum exact);
// Mobius fused into GEMM epilogue via 8-block row-group sync (device-scope atomics,
// REGULAR launch: grid=256=CU count, 1 block/CU forced by 128KB LDS -> co-resident).
#define M_DIM 8192
#define K_DIM 2048
#define N_DIM 2048

#define BM 256
#define BN 256
#define BKB 128            // K-tile bytes; row = 128 B = 8 x 16B chunks
#define NT (K_DIM / BKB)   // 16

typedef __attribute__((ext_vector_type(4))) int int32x4;
typedef __attribute__((ext_vector_type(16))) int int32x16;
typedef __attribute__((ext_vector_type(4))) float float4v;

#define GLD16(gp, lp)                                                          \
    __builtin_amdgcn_global_load_lds(                                          \
        (const __attribute__((address_space(1))) void*)(gp),                   \
        (__attribute__((address_space(3))) void*)(lp), 16, 0, 0)

#define BAR()                                                                  \
    do {                                                                       \
        asm volatile("" ::: "memory");                                         \
        __builtin_amdgcn_s_barrier();                                          \
        asm volatile("" ::: "memory");                                         \
    } while (0)

#define VMCNT(n) asm volatile("s_waitcnt vmcnt(" #n ")" ::: "memory")

// ---------------- merged prepass: W transpose->i8 (blocks 0..4095) + x quant (4096..12287) ----
__global__ __launch_bounds__(256) void prep_kernel(const float* __restrict__ W,
                                                   const float* __restrict__ X,
                                                   signed char* __restrict__ Wq,
                                                   signed char* __restrict__ Xq,
                                                   float* __restrict__ srow) {
    __shared__ float tile[32][33];
    __shared__ float wm[4];
    const int bid = blockIdx.x;
    if (bid < 4096) {
        // ---- transpose W (K x N fp32 ternary) -> Wq (N x K i8) ----
        const int kb = (bid & 63) * 32;
        const int nb = (bid >> 6) * 32;
        const int tx = threadIdx.x & 31;
        const int ty4 = (threadIdx.x >> 5) * 4;
#pragma unroll
        for (int i = 0; i < 4; i++)
            tile[ty4 + i][tx] = W[(size_t)(kb + ty4 + i) * N_DIM + nb + tx];
        __syncthreads();
        const int r = threadIdx.x >> 3;
        const int c4 = threadIdx.x & 7;
        uint32_t pk = 0;
#pragma unroll
        for (int j = 0; j < 4; j++) {
            const int q = (int)tile[c4 * 4 + j][r];
            pk |= (uint32_t)(q & 255) << (8 * j);
        }
        *(uint32_t*)&Wq[(size_t)(nb + r) * K_DIM + kb + c4 * 4] = pk;
    } else {
        // ---- quantize x row -> i8 with per-row scale ----
        const int row = bid - 4096;
        const int t = threadIdx.x;
        const float* p = X + (size_t)row * K_DIM;
        float4v a = *(const float4v*)&p[t * 8];
        float4v b = *(const float4v*)&p[t * 8 + 4];
        float m = 0.f;
#pragma unroll
        for (int j = 0; j < 4; j++) m = fmaxf(m, fmaxf(fabsf(a[j]), fabsf(b[j])));
#pragma unroll
        for (int off = 1; off < 64; off <<= 1) m = fmaxf(m, __shfl_xor(m, off));
        if ((t & 63) == 0) wm[t >> 6] = m;
        __syncthreads();
        float bm = fmaxf(fmaxf(wm[0], wm[1]), fmaxf(wm[2], wm[3]));
        bm = fmaxf(bm, 1e-8f);
        const float inv = 127.f / bm;
        uint32_t lo = 0, hi = 0;
#pragma unroll
        for (int j = 0; j < 4; j++) {
            const int qa = __float2int_rn(a[j] * inv);
            const int qb = __float2int_rn(b[j] * inv);
            lo |= (uint32_t)(qa & 255) << (8 * j);
            hi |= (uint32_t)(qb & 255) << (8 * j);
        }
        uint32_t* q = (uint32_t*)&Xq[(size_t)row * K_DIM + t * 8];
        q[0] = lo;
        q[1] = hi;
        if (t == 0) srow[row] = bm / 127.f;
    }
}

// ---------------- fused GEMM + Mobius ----------------
// Main loop: R15-verified (free-run, 1 barrier/tile, VMCNT(0) before BAR,
// conflict-free swizzle swz(r) = (r&7)^((r>>3)&3), 0 bank conflicts).
// Epilogue (R10-validated protocol): in-LDS row-sumsq reduce -> agent-scope
// relaxed publish -> __syncthreads -> acq_rel counter -> acquire spin (8 blocks
// sharing mt) -> per-row gain -> direct fp32 out write from registers.
__global__ __launch_bounds__(512, 1) void gemm_i8_fused(const signed char* __restrict__ Xq,
                                                        const signed char* __restrict__ Wq,
                                                        const float* __restrict__ scale,
                                                        const float* __restrict__ srow,
                                                        float* __restrict__ out,
                                                        float* __restrict__ wsp,
                                                        int* __restrict__ cnt) {
    __shared__ __align__(16) ushort lds[65536];   // 128 KiB tiles; reused as float[32768]

    const int tid = threadIdx.x;
    const int w = tid >> 6;            // wave 0..7
    const int lane = tid & 63;
    const int lrow = lane & 31;
    const int khalf = lane >> 5;
    const int rswz = (lrow & 7) ^ ((lrow >> 3) & 3);   // R15 conflict-free read XOR

    // XCD-chunked bijective swizzle (nwg=256, 8 XCDs): 8 nt-peers of an mt span all XCDs
    const int bid = blockIdx.x;
    const int wg = (bid & 7) * 32 + (bid >> 3);
    const int mt = wg >> 3;            // 0..31 row-group
    const int nt = wg & 7;             // 0..7 col-group
    const int row0 = mt * BM;
    const int col0 = nt * BN;

    const int wr = (w >> 2) * 128;
    const int wc = (w & 3) * 64;
    const int whalfA = w >> 2;
    const int whalfB = (w & 3) >> 1;
    const int wrB = (w & 1) * 64;

    int r_[2], c8_[2];
#pragma unroll
    for (int i = 0; i < 2; ++i) {
        const int q = (i * 8 + w) * 64 + lane;
        const int r = q >> 3;
        r_[i] = r;
        c8_[i] = (q & 7) ^ ((r & 7) ^ ((r >> 3) & 3));   // inverse of read swizzle
    }

    auto stage2 = [&](const signed char* sb, int ldsbase) {
        GLD16(sb + (size_t)r_[0] * K_DIM + c8_[0] * 16, lds + ldsbase + (0 * 8 + w) * 512);
        GLD16(sb + (size_t)r_[1] * K_DIM + c8_[1] * 16, lds + ldsbase + (1 * 8 + w) * 512);
    };

#define RD_A(m, kk, base) (*(const int32x4*)&lds[(base) + ((m) * 32 + lrow) * 64 + ((((kk) * 2 + khalf) ^ rswz) * 8)])
#define RD_B(n, kk, base) (*(const int32x4*)&lds[(base) + (wrB + (n) * 32 + lrow) * 64 + ((((kk) * 2 + khalf) ^ rswz) * 8)])

    int32x16 acc[4][2] = {};

    const signed char* Asrc0 = Xq + (size_t)row0 * K_DIM;
    const signed char* Asrc1 = Xq + (size_t)(row0 + 128) * K_DIM;
    const signed char* Bsrc0 = Wq + (size_t)col0 * K_DIM;
    const signed char* Bsrc1 = Wq + (size_t)(col0 + 128) * K_DIM;

    stage2(Asrc0, 0 * 8192);
    stage2(Asrc1, 1 * 8192);
    stage2(Bsrc0, 32768 + 0 * 8192);
    stage2(Bsrc1, 32768 + 1 * 8192);
    VMCNT(0);
    BAR();

    for (int t = 0; t < NT; ++t) {
        const int abase = ((2 * t + whalfA) & 3) * 8192;
        const int bbase = 32768 + ((2 * t + whalfB) & 3) * 8192;
        const bool pf = (t + 1 < NT);
        const int aslot0 = ((2 * (t + 1)) & 3) * 8192;
        const int aslot1 = ((2 * (t + 1) + 1) & 3) * 8192;
        const int bslot0 = 32768 + ((2 * (t + 1)) & 3) * 8192;
        const int bslot1 = 32768 + ((2 * (t + 1) + 1) & 3) * 8192;

        if (pf) {
            stage2(Asrc0 + (t + 1) * BKB, aslot0);
            stage2(Asrc1 + (t + 1) * BKB, aslot1);
            stage2(Bsrc0 + (t + 1) * BKB, bslot0);
            stage2(Bsrc1 + (t + 1) * BKB, bslot1);
        }

#pragma unroll
        for (int kk = 0; kk < 4; ++kk) {
            int32x4 bfr[2], afr[4];
#pragma unroll
            for (int n = 0; n < 2; ++n) bfr[n] = RD_B(n, kk, bbase);
#pragma unroll
            for (int m = 0; m < 4; ++m) afr[m] = RD_A(m, kk, abase);
            __builtin_amdgcn_s_setprio(1);
#pragma unroll
            for (int m = 0; m < 4; ++m)
#pragma unroll
                for (int n = 0; n < 2; ++n)
                    acc[m][n] = __builtin_amdgcn_mfma_i32_32x32x32_i8(afr[m], bfr[n], acc[m][n], 0, 0, 0);
            __builtin_amdgcn_s_setprio(0);
        }

        VMCNT(0);
        BAR();
    }

    // ================= fused Mobius epilogue (R10 protocol) =================
    float* lf = (float*)lds;                  // [256 rows][128 col-slots]
    const int ccolb = col0 + wc + lrow;       // lane's col (+n*32)
    const float sc0 = scale[ccolb];
    const float sc1 = scale[ccolb + 32];
    __syncthreads();                          // all tile reads done; LDS reusable

    // 1) per-lane sumsq over its 2 cols -> lf[row_local][(w&3)*32+lrow]
#pragma unroll
    for (int m = 0; m < 4; ++m) {
#pragma unroll
        for (int r = 0; r < 16; ++r) {
            const int row_local = wr + 4 * khalf + m * 32 + (r & 3) + 8 * (r >> 2);
            const float a0 = (float)acc[m][0][r] * sc0;
            const float a1 = (float)acc[m][1][r] * sc1;
            lf[row_local * 128 + (w & 3) * 32 + lrow] = a0 * a0 + a1 * a1;
        }
    }
    __syncthreads();

    // 2) per-row partial (128 slots, rotation-indexed: conflict-free) -> publish
    if (tid < 256) {
        float s = 0.f;
        const int base = tid * 128;
#pragma unroll 8
        for (int e = 0; e < 128; ++e) s += lf[base + ((e + tid) & 127)];
        __hip_atomic_store(&wsp[(size_t)(row0 + tid) * 8 + nt], s,
                           __ATOMIC_RELAXED, __HIP_MEMORY_SCOPE_AGENT);
    }
    __syncthreads();

    // 3) 8-block group sync on cnt[mt] (all blocks co-resident: grid=256, 1/CU)
    if (tid == 0) {
        __hip_atomic_fetch_add(&cnt[mt], 1, __ATOMIC_ACQ_REL, __HIP_MEMORY_SCOPE_AGENT);
        while (__hip_atomic_load(&cnt[mt], __ATOMIC_ACQUIRE, __HIP_MEMORY_SCOPE_AGENT) < 8)
            __builtin_amdgcn_s_sleep(8);
    }
    __syncthreads();

    // 4) per-row gain -> lf[0..255]
    if (tid < 256) {
        float tot = 0.f;
#pragma unroll
        for (int j = 0; j < 8; ++j)
            tot += __hip_atomic_load(&wsp[(size_t)(row0 + tid) * 8 + j],
                                     __ATOMIC_RELAXED, __HIP_MEMORY_SCOPE_AGENT);
        const float s = srow[row0 + tid];
        tot *= s * s;
        const float vn = fmaxf(sqrtf(tot), 1e-7f);
        const float tf = tanhf(vn) / (vn + 1e-7f);
        const float on = fmaxf(tf * vn, 1e-7f);
        lf[tid] = s * tf * fminf(0.99f / on, 1.0f);
    }
    __syncthreads();

    // 5) direct C-write from registers: out = acc * scale * g[row]
#pragma unroll
    for (int m = 0; m < 4; ++m) {
#pragma unroll
        for (int r = 0; r < 16; ++r) {
            const int row_local = wr + 4 * khalf + m * 32 + (r & 3) + 8 * (r >> 2);
            const float g = lf[row_local];
            float* o = out + (size_t)(row0 + row_local) * N_DIM;
            o[ccolb] = (float)acc[m][0][r] * sc0 * g;
            o[ccolb + 32] = (float)acc[m][1][r] * sc1 * g;
        }
    }
#undef RD_A
#undef RD_B
}

extern "C" void kernel_launch(void* const* d_in, const int* in_sizes, int n_in,
                              void* d_out, int out_size, void* d_ws, size_t ws_size,
                              hipStream_t stream) {
    const float* x = (const float*)d_in[0];
    const float* w = (const float*)d_in[1];
    const float* scale = (const float*)d_in[2];
    float* out = (float*)d_out;

    // ws layout: Wq @0 (4 MB), Xq @4M (16 MB), srow @20971520 (32 KB),
    //            wsp @21037056 (256 KB), cnt @21299200 (128 B)
    signed char* Wq = (signed char*)d_ws;
    signed char* Xq = (signed char*)d_ws + 4194304;
    float* srow = (float*)((char*)d_ws + 20971520);
    float* wsp = (float*)((char*)d_ws + 21037056);
    int* cnt = (int*)((char*)d_ws + 21299200);

    hipMemsetAsync(cnt, 0, 32 * sizeof(int), stream);   // fresh group counters every call
    prep_kernel<<<dim3(4096 + 8192), dim3(256), 0, stream>>>(w, x, Wq, Xq, srow);
    gemm_i8_fused<<<dim3(256), dim3(512), 0, stream>>>(Xq, Wq, scale, srow, out, wsp, cnt);
}

// Round 17
// 79.243 us; speedup vs baseline: 1.0753x; 1.0753x over previous
//
#include <hip/hip_runtime.h>
#include <hip/hip_bf16.h>
#include <stdint.h>
#include <math.h>

// TernaryMobiusLinear: out = mobius( (x @ W) * scale ), x 8192x2048 fp32, W ternary.
// Final assembly (R17): merged prep (1 launch) + R15 conflict-free i8 GEMM + mobius.
// Path: x -> i8 per-row quant (scale folded into epilogue); W -> i8 exact (ternary);
// 32x32x32 i8 MFMA GEMM (i32 accum exact); bf16 intermediate C; Mobius epilogue.
#define M_DIM 8192
#define K_DIM 2048
#define N_DIM 2048

#define BM 256
#define BN 256
#define BKB 128            // K-tile bytes; row = 128 B = 8 x 16B chunks
#define NT (K_DIM / BKB)   // 16

typedef __attribute__((ext_vector_type(4))) int int32x4;
typedef __attribute__((ext_vector_type(16))) int int32x16;
typedef __attribute__((ext_vector_type(4))) float float4v;

__device__ __forceinline__ ushort f2bf(float f) {
    uint32_t u = __builtin_bit_cast(uint32_t, f);
    u = (u + 0x7fffu + ((u >> 16) & 1u)) >> 16;
    return (ushort)u;
}

#define GLD16(gp, lp)                                                          \
    __builtin_amdgcn_global_load_lds(                                          \
        (const __attribute__((address_space(1))) void*)(gp),                   \
        (__attribute__((address_space(3))) void*)(lp), 16, 0, 0)

#define BAR()                                                                  \
    do {                                                                       \
        asm volatile("" ::: "memory");                                         \
        __builtin_amdgcn_s_barrier();                                          \
        asm volatile("" ::: "memory");                                         \
    } while (0)

#define VMCNT(n) asm volatile("s_waitcnt vmcnt(" #n ")" ::: "memory")

// ---------------- merged prepass: W transpose->i8 (blocks 0..4095) + x quant (4096..12287) ----
__global__ __launch_bounds__(256) void prep_kernel(const float* __restrict__ W,
                                                   const float* __restrict__ X,
                                                   signed char* __restrict__ Wq,
                                                   signed char* __restrict__ Xq,
                                                   float* __restrict__ srow) {
    __shared__ float tile[32][33];
    __shared__ float wm[4];
    const int bid = blockIdx.x;
    if (bid < 4096) {
        // ---- transpose W (K x N fp32 ternary) -> Wq (N x K i8) ----
        const int kb = (bid & 63) * 32;
        const int nb = (bid >> 6) * 32;
        const int tx = threadIdx.x & 31;
        const int ty4 = (threadIdx.x >> 5) * 4;
#pragma unroll
        for (int i = 0; i < 4; i++)
            tile[ty4 + i][tx] = W[(size_t)(kb + ty4 + i) * N_DIM + nb + tx];
        __syncthreads();
        const int r = threadIdx.x >> 3;
        const int c4 = threadIdx.x & 7;
        uint32_t pk = 0;
#pragma unroll
        for (int j = 0; j < 4; j++) {
            const int q = (int)tile[c4 * 4 + j][r];
            pk |= (uint32_t)(q & 255) << (8 * j);
        }
        *(uint32_t*)&Wq[(size_t)(nb + r) * K_DIM + kb + c4 * 4] = pk;
    } else {
        // ---- quantize x row -> i8 with per-row scale ----
        const int row = bid - 4096;
        const int t = threadIdx.x;
        const float* p = X + (size_t)row * K_DIM;
        float4v a = *(const float4v*)&p[t * 8];
        float4v b = *(const float4v*)&p[t * 8 + 4];
        float m = 0.f;
#pragma unroll
        for (int j = 0; j < 4; j++) m = fmaxf(m, fmaxf(fabsf(a[j]), fabsf(b[j])));
#pragma unroll
        for (int off = 1; off < 64; off <<= 1) m = fmaxf(m, __shfl_xor(m, off));
        if ((t & 63) == 0) wm[t >> 6] = m;
        __syncthreads();
        float bm = fmaxf(fmaxf(wm[0], wm[1]), fmaxf(wm[2], wm[3]));
        bm = fmaxf(bm, 1e-8f);
        const float inv = 127.f / bm;
        uint32_t lo = 0, hi = 0;
#pragma unroll
        for (int j = 0; j < 4; j++) {
            const int qa = __float2int_rn(a[j] * inv);
            const int qb = __float2int_rn(b[j] * inv);
            lo |= (uint32_t)(qa & 255) << (8 * j);
            hi |= (uint32_t)(qb & 255) << (8 * j);
        }
        uint32_t* q = (uint32_t*)&Xq[(size_t)row * K_DIM + t * 8];
        q[0] = lo;
        q[1] = hi;
        if (t == 0) srow[row] = bm / 127.f;
    }
}

// ---------------- GEMM: Cb = bf16( (Xq @ Wq^T) * scale ), i32 accum exact ----------------
// 256x256 tile, BKB=128, 8 waves (2M x 4N), per-wave C = 128x64 = 4x2 frags of 32x32.
// Free-run schedule (R7-verified): one barrier per K-tile; stage tile t+1 at tile
// top into t-1's slots; VMCNT(0) BEFORE tile-end BAR (R5 lesson).
// LDS swizzle (R15-verified, 0 conflicts): chunk (r,c) at slot c ^ swz(r),
//   swz(r) = (r&7) ^ ((r>>3)&3); both-sides (pre-swizzled source + read XOR).
__global__ __launch_bounds__(512, 1) void gemm_i8(const signed char* __restrict__ Xq,
                                                  const signed char* __restrict__ Wq,
                                                  const float* __restrict__ scale,
                                                  ushort* __restrict__ Cb) {
    __shared__ __align__(16) ushort lds[65536];   // 128 KiB: A [0,32768), B [32768,65536)

    const int tid = threadIdx.x;
    const int w = tid >> 6;            // wave 0..7
    const int lane = tid & 63;
    const int lrow = lane & 31;        // row|col within 32x32 frag
    const int khalf = lane >> 5;       // 0..1: which 16B chunk within K=32
    const int rswz = (lrow & 7) ^ ((lrow >> 3) & 3);   // read-side XOR (chunk units)

    // XCD-chunked bijective swizzle (nwg=256, 8 XCDs)
    const int bid = blockIdx.x;
    const int wg = (bid & 7) * 32 + (bid >> 3);
    const int mt = wg >> 3;            // 0..31
    const int nt = wg & 7;             // 0..7
    const int row0 = mt * BM;
    const int col0 = nt * BN;

    const int wr = (w >> 2) * 128;     // wave M offset
    const int wc = (w & 3) * 64;       // wave N offset
    const int whalfA = w >> 2;
    const int whalfB = (w & 3) >> 1;
    const int wrB = (w & 1) * 64;      // row offset within B half

    int r_[2], c8_[2];
#pragma unroll
    for (int i = 0; i < 2; ++i) {
        const int q = (i * 8 + w) * 64 + lane;
        const int r = q >> 3;
        r_[i] = r;
        c8_[i] = (q & 7) ^ ((r & 7) ^ ((r >> 3) & 3));   // inverse of read swizzle
    }

    auto stage2 = [&](const signed char* sb, int ldsbase) {
        GLD16(sb + (size_t)r_[0] * K_DIM + c8_[0] * 16, lds + ldsbase + (0 * 8 + w) * 512);
        GLD16(sb + (size_t)r_[1] * K_DIM + c8_[1] * 16, lds + ldsbase + (1 * 8 + w) * 512);
    };

// ushort-unit indexing: row stride 64 ushorts = 128 B; chunk = 8 ushorts = 16 B.
#define RD_A(m, kk, base) (*(const int32x4*)&lds[(base) + ((m) * 32 + lrow) * 64 + ((((kk) * 2 + khalf) ^ rswz) * 8)])
#define RD_B(n, kk, base) (*(const int32x4*)&lds[(base) + (wrB + (n) * 32 + lrow) * 64 + ((((kk) * 2 + khalf) ^ rswz) * 8)])

    int32x16 acc[4][2] = {};

    const signed char* Asrc0 = Xq + (size_t)row0 * K_DIM;
    const signed char* Asrc1 = Xq + (size_t)(row0 + 128) * K_DIM;
    const signed char* Bsrc0 = Wq + (size_t)col0 * K_DIM;
    const signed char* Bsrc1 = Wq + (size_t)(col0 + 128) * K_DIM;

    // prologue: stage tile 0, drain, barrier
    stage2(Asrc0, 0 * 8192);
    stage2(Asrc1, 1 * 8192);
    stage2(Bsrc0, 32768 + 0 * 8192);
    stage2(Bsrc1, 32768 + 1 * 8192);
    VMCNT(0);
    BAR();

    for (int t = 0; t < NT; ++t) {
        const int abase = ((2 * t + whalfA) & 3) * 8192;
        const int bbase = 32768 + ((2 * t + whalfB) & 3) * 8192;
        const bool pf = (t + 1 < NT);
        const int aslot0 = ((2 * (t + 1)) & 3) * 8192;
        const int aslot1 = ((2 * (t + 1) + 1) & 3) * 8192;
        const int bslot0 = 32768 + ((2 * (t + 1)) & 3) * 8192;
        const int bslot1 = 32768 + ((2 * (t + 1) + 1) & 3) * 8192;

        // stage tile t+1 fully, earliest (into t-1's slots; max drain cover)
        if (pf) {
            stage2(Asrc0 + (t + 1) * BKB, aslot0);
            stage2(Asrc1 + (t + 1) * BKB, aslot1);
            stage2(Bsrc0 + (t + 1) * BKB, bslot0);
            stage2(Bsrc1 + (t + 1) * BKB, bslot1);
        }

        // free-run compute: 4 kk steps (K=32 each), no intra-tile barriers
#pragma unroll
        for (int kk = 0; kk < 4; ++kk) {
            int32x4 bfr[2], afr[4];
#pragma unroll
            for (int n = 0; n < 2; ++n) bfr[n] = RD_B(n, kk, bbase);
#pragma unroll
            for (int m = 0; m < 4; ++m) afr[m] = RD_A(m, kk, abase);
            __builtin_amdgcn_s_setprio(1);
#pragma unroll
            for (int m = 0; m < 4; ++m)
#pragma unroll
                for (int n = 0; n < 2; ++n)
                    acc[m][n] = __builtin_amdgcn_mfma_i32_32x32x32_i8(afr[m], bfr[n], acc[m][n], 0, 0, 0);
            __builtin_amdgcn_s_setprio(0);
        }

        // tile boundary: drain own staging BEFORE barrier (R5 lesson)
        VMCNT(0);
        BAR();
    }

    // epilogue: Cb = bf16( acc * scale[col] )   (row scale folded into mobius)
    const int ccolb = col0 + wc + lrow;           // + n*32
    const int crowb = row0 + wr + 4 * khalf;      // + m*32 + (reg&3) + 8*(reg>>2)
#pragma unroll
    for (int n = 0; n < 2; ++n) {
        const float sc = scale[ccolb + n * 32];
#pragma unroll
        for (int m = 0; m < 4; ++m) {
#pragma unroll
            for (int r = 0; r < 16; ++r) {
                const int row = crowb + m * 32 + (r & 3) + 8 * (r >> 2);
                const float v = (float)acc[m][n][r] * sc;
                Cb[(size_t)row * N_DIM + ccolb + n * 32] = f2bf(v);
            }
        }
    }
#undef RD_A
#undef RD_B
}

// ---------------- Mobius epilogue: out = srow * Cb * gain(norm(srow*Cb)) ----------------
__global__ __launch_bounds__(256) void mobius_bf16(const ushort* __restrict__ Cb,
                                                   const float* __restrict__ srow,
                                                   float* __restrict__ out) {
    const int row = blockIdx.x;
    const ushort* p = Cb + (size_t)row * N_DIM;
    float* q = out + (size_t)row * N_DIM;
    const int t = threadIdx.x;
    const float s = srow[row];

    typedef __attribute__((ext_vector_type(8))) short short8;
    short8 v = *(const short8*)&p[t * 8];
    float f[8];
#pragma unroll
    for (int j = 0; j < 8; ++j) {
        const uint32_t u = ((uint32_t)(uint16_t)v[j]) << 16;
        f[j] = __builtin_bit_cast(float, u);
    }
    float ss = 0.f;
#pragma unroll
    for (int j = 0; j < 8; ++j) ss += f[j] * f[j];
#pragma unroll
    for (int off = 1; off < 64; off <<= 1) ss += __shfl_xor(ss, off);
    __shared__ float wsum[4];
    if ((t & 63) == 0) wsum[t >> 6] = ss;
    __syncthreads();
    const float tot = (wsum[0] + wsum[1] + wsum[2] + wsum[3]) * s * s;
    const float vn = fmaxf(sqrtf(tot), 1e-7f);
    const float tf = tanhf(vn) / (vn + 1e-7f);
    const float on = fmaxf(tf * vn, 1e-7f);
    const float g = s * tf * fminf(0.99f / on, 1.0f);
    float4v o0, o1;
#pragma unroll
    for (int j = 0; j < 4; ++j) { o0[j] = f[j] * g; o1[j] = f[4 + j] * g; }
    *(float4v*)&q[t * 8] = o0;
    *(float4v*)&q[t * 8 + 4] = o1;
}

extern "C" void kernel_launch(void* const* d_in, const int* in_sizes, int n_in,
                              void* d_out, int out_size, void* d_ws, size_t ws_size,
                              hipStream_t stream) {
    const float* x = (const float*)d_in[0];
    const float* w = (const float*)d_in[1];
    const float* scale = (const float*)d_in[2];
    float* out = (float*)d_out;

    // ws layout: Wq @0 (4 MB), Xq @4M (16 MB), srow @20971520 (32 KB), Cb @21037056 (32 MB)
    signed char* Wq = (signed char*)d_ws;
    signed char* Xq = (signed char*)d_ws + 4194304;
    float* srow = (float*)((char*)d_ws + 20971520);
    ushort* Cb = (ushort*)((char*)d_ws + 21037056);

    prep_kernel<<<dim3(4096 + 8192), dim3(256), 0, stream>>>(w, x, Wq, Xq, srow);
    gemm_i8<<<dim3((M_DIM / BM) * (N_DIM / BN)), dim3(512), 0, stream>>>(Xq, Wq, scale, Cb);
    mobius_bf16<<<dim3(M_DIM), dim3(256), 0, stream>>>(Cb, srow, out);
}

// Round 18
// 78.198 us; speedup vs baseline: 1.0897x; 1.0134x over previous
//
#include <hip/hip_runtime.h>
#include <hip/hip_bf16.h>
#include <stdint.h>
#include <math.h>

// TernaryMobiusLinear: out = mobius( (x @ W) * scale ), x 8192x2048 fp32, W ternary.
// Final (R18): R17 + epilogue store-order fix (n innermost -> 128B-line write combining).
// Path: x -> i8 per-row quant (scale folded into epilogue); W -> i8 exact (ternary);
// 32x32x32 i8 MFMA GEMM (i32 accum exact); bf16 intermediate C; Mobius epilogue.
#define M_DIM 8192
#define K_DIM 2048
#define N_DIM 2048

#define BM 256
#define BN 256
#define BKB 128            // K-tile bytes; row = 128 B = 8 x 16B chunks
#define NT (K_DIM / BKB)   // 16

typedef __attribute__((ext_vector_type(4))) int int32x4;
typedef __attribute__((ext_vector_type(16))) int int32x16;
typedef __attribute__((ext_vector_type(4))) float float4v;

__device__ __forceinline__ ushort f2bf(float f) {
    uint32_t u = __builtin_bit_cast(uint32_t, f);
    u = (u + 0x7fffu + ((u >> 16) & 1u)) >> 16;
    return (ushort)u;
}

#define GLD16(gp, lp)                                                          \
    __builtin_amdgcn_global_load_lds(                                          \
        (const __attribute__((address_space(1))) void*)(gp),                   \
        (__attribute__((address_space(3))) void*)(lp), 16, 0, 0)

#define BAR()                                                                  \
    do {                                                                       \
        asm volatile("" ::: "memory");                                         \
        __builtin_amdgcn_s_barrier();                                          \
        asm volatile("" ::: "memory");                                         \
    } while (0)

#define VMCNT(n) asm volatile("s_waitcnt vmcnt(" #n ")" ::: "memory")

// ---------------- merged prepass: W transpose->i8 (blocks 0..4095) + x quant (4096..12287) ----
__global__ __launch_bounds__(256) void prep_kernel(const float* __restrict__ W,
                                                   const float* __restrict__ X,
                                                   signed char* __restrict__ Wq,
                                                   signed char* __restrict__ Xq,
                                                   float* __restrict__ srow) {
    __shared__ float tile[32][33];
    __shared__ float wm[4];
    const int bid = blockIdx.x;
    if (bid < 4096) {
        // ---- transpose W (K x N fp32 ternary) -> Wq (N x K i8) ----
        const int kb = (bid & 63) * 32;
        const int nb = (bid >> 6) * 32;
        const int tx = threadIdx.x & 31;
        const int ty4 = (threadIdx.x >> 5) * 4;
#pragma unroll
        for (int i = 0; i < 4; i++)
            tile[ty4 + i][tx] = W[(size_t)(kb + ty4 + i) * N_DIM + nb + tx];
        __syncthreads();
        const int r = threadIdx.x >> 3;
        const int c4 = threadIdx.x & 7;
        uint32_t pk = 0;
#pragma unroll
        for (int j = 0; j < 4; j++) {
            const int q = (int)tile[c4 * 4 + j][r];
            pk |= (uint32_t)(q & 255) << (8 * j);
        }
        *(uint32_t*)&Wq[(size_t)(nb + r) * K_DIM + kb + c4 * 4] = pk;
    } else {
        // ---- quantize x row -> i8 with per-row scale ----
        const int row = bid - 4096;
        const int t = threadIdx.x;
        const float* p = X + (size_t)row * K_DIM;
        float4v a = *(const float4v*)&p[t * 8];
        float4v b = *(const float4v*)&p[t * 8 + 4];
        float m = 0.f;
#pragma unroll
        for (int j = 0; j < 4; j++) m = fmaxf(m, fmaxf(fabsf(a[j]), fabsf(b[j])));
#pragma unroll
        for (int off = 1; off < 64; off <<= 1) m = fmaxf(m, __shfl_xor(m, off));
        if ((t & 63) == 0) wm[t >> 6] = m;
        __syncthreads();
        float bm = fmaxf(fmaxf(wm[0], wm[1]), fmaxf(wm[2], wm[3]));
        bm = fmaxf(bm, 1e-8f);
        const float inv = 127.f / bm;
        uint32_t lo = 0, hi = 0;
#pragma unroll
        for (int j = 0; j < 4; j++) {
            const int qa = __float2int_rn(a[j] * inv);
            const int qb = __float2int_rn(b[j] * inv);
            lo |= (uint32_t)(qa & 255) << (8 * j);
            hi |= (uint32_t)(qb & 255) << (8 * j);
        }
        uint32_t* q = (uint32_t*)&Xq[(size_t)row * K_DIM + t * 8];
        q[0] = lo;
        q[1] = hi;
        if (t == 0) srow[row] = bm / 127.f;
    }
}

// ---------------- GEMM: Cb = bf16( (Xq @ Wq^T) * scale ), i32 accum exact ----------------
// 256x256 tile, BKB=128, 8 waves (2M x 4N), per-wave C = 128x64 = 4x2 frags of 32x32.
// Free-run schedule (R7-verified): one barrier per K-tile; stage tile t+1 at tile
// top into t-1's slots; VMCNT(0) BEFORE tile-end BAR (R5 lesson).
// LDS swizzle (R15-verified, 0 conflicts): chunk (r,c) at slot c ^ swz(r),
//   swz(r) = (r&7) ^ ((r>>3)&3); both-sides (pre-swizzled source + read XOR).
__global__ __launch_bounds__(512, 1) void gemm_i8(const signed char* __restrict__ Xq,
                                                  const signed char* __restrict__ Wq,
                                                  const float* __restrict__ scale,
                                                  ushort* __restrict__ Cb) {
    __shared__ __align__(16) ushort lds[65536];   // 128 KiB: A [0,32768), B [32768,65536)

    const int tid = threadIdx.x;
    const int w = tid >> 6;            // wave 0..7
    const int lane = tid & 63;
    const int lrow = lane & 31;        // row|col within 32x32 frag
    const int khalf = lane >> 5;       // 0..1: which 16B chunk within K=32
    const int rswz = (lrow & 7) ^ ((lrow >> 3) & 3);   // read-side XOR (chunk units)

    // XCD-chunked bijective swizzle (nwg=256, 8 XCDs)
    const int bid = blockIdx.x;
    const int wg = (bid & 7) * 32 + (bid >> 3);
    const int mt = wg >> 3;            // 0..31
    const int nt = wg & 7;             // 0..7
    const int row0 = mt * BM;
    const int col0 = nt * BN;

    const int wr = (w >> 2) * 128;     // wave M offset
    const int wc = (w & 3) * 64;       // wave N offset
    const int whalfA = w >> 2;
    const int whalfB = (w & 3) >> 1;
    const int wrB = (w & 1) * 64;      // row offset within B half

    int r_[2], c8_[2];
#pragma unroll
    for (int i = 0; i < 2; ++i) {
        const int q = (i * 8 + w) * 64 + lane;
        const int r = q >> 3;
        r_[i] = r;
        c8_[i] = (q & 7) ^ ((r & 7) ^ ((r >> 3) & 3));   // inverse of read swizzle
    }

    auto stage2 = [&](const signed char* sb, int ldsbase) {
        GLD16(sb + (size_t)r_[0] * K_DIM + c8_[0] * 16, lds + ldsbase + (0 * 8 + w) * 512);
        GLD16(sb + (size_t)r_[1] * K_DIM + c8_[1] * 16, lds + ldsbase + (1 * 8 + w) * 512);
    };

// ushort-unit indexing: row stride 64 ushorts = 128 B; chunk = 8 ushorts = 16 B.
#define RD_A(m, kk, base) (*(const int32x4*)&lds[(base) + ((m) * 32 + lrow) * 64 + ((((kk) * 2 + khalf) ^ rswz) * 8)])
#define RD_B(n, kk, base) (*(const int32x4*)&lds[(base) + (wrB + (n) * 32 + lrow) * 64 + ((((kk) * 2 + khalf) ^ rswz) * 8)])

    int32x16 acc[4][2] = {};

    const signed char* Asrc0 = Xq + (size_t)row0 * K_DIM;
    const signed char* Asrc1 = Xq + (size_t)(row0 + 128) * K_DIM;
    const signed char* Bsrc0 = Wq + (size_t)col0 * K_DIM;
    const signed char* Bsrc1 = Wq + (size_t)(col0 + 128) * K_DIM;

    // prologue: stage tile 0, drain, barrier
    stage2(Asrc0, 0 * 8192);
    stage2(Asrc1, 1 * 8192);
    stage2(Bsrc0, 32768 + 0 * 8192);
    stage2(Bsrc1, 32768 + 1 * 8192);
    VMCNT(0);
    BAR();

    for (int t = 0; t < NT; ++t) {
        const int abase = ((2 * t + whalfA) & 3) * 8192;
        const int bbase = 32768 + ((2 * t + whalfB) & 3) * 8192;
        const bool pf = (t + 1 < NT);
        const int aslot0 = ((2 * (t + 1)) & 3) * 8192;
        const int aslot1 = ((2 * (t + 1) + 1) & 3) * 8192;
        const int bslot0 = 32768 + ((2 * (t + 1)) & 3) * 8192;
        const int bslot1 = 32768 + ((2 * (t + 1) + 1) & 3) * 8192;

        // stage tile t+1 fully, earliest (into t-1's slots; max drain cover)
        if (pf) {
            stage2(Asrc0 + (t + 1) * BKB, aslot0);
            stage2(Asrc1 + (t + 1) * BKB, aslot1);
            stage2(Bsrc0 + (t + 1) * BKB, bslot0);
            stage2(Bsrc1 + (t + 1) * BKB, bslot1);
        }

        // free-run compute: 4 kk steps (K=32 each), no intra-tile barriers
#pragma unroll
        for (int kk = 0; kk < 4; ++kk) {
            int32x4 bfr[2], afr[4];
#pragma unroll
            for (int n = 0; n < 2; ++n) bfr[n] = RD_B(n, kk, bbase);
#pragma unroll
            for (int m = 0; m < 4; ++m) afr[m] = RD_A(m, kk, abase);
            __builtin_amdgcn_s_setprio(1);
#pragma unroll
            for (int m = 0; m < 4; ++m)
#pragma unroll
                for (int n = 0; n < 2; ++n)
                    acc[m][n] = __builtin_amdgcn_mfma_i32_32x32x32_i8(afr[m], bfr[n], acc[m][n], 0, 0, 0);
            __builtin_amdgcn_s_setprio(0);
        }

        // tile boundary: drain own staging BEFORE barrier (R5 lesson)
        VMCNT(0);
        BAR();
    }

    // epilogue: Cb = bf16( acc * scale[col] )   (row scale folded into mobius)
    // Store order: n INNERMOST so the two 64B halves of each 128B line (cols
    // wc..wc+31 and wc+32..wc+63 of one row) are written back-to-back -> the
    // write combiner merges them before eviction (R17 showed 48.7MB WRITE for
    // a 32MB surface with n outermost).
    const int ccolb = col0 + wc + lrow;           // + n*32
    const int crowb = row0 + wr + 4 * khalf;      // + m*32 + (reg&3) + 8*(reg>>2)
    const float sc0 = scale[ccolb];
    const float sc1 = scale[ccolb + 32];
#pragma unroll
    for (int m = 0; m < 4; ++m) {
#pragma unroll
        for (int r = 0; r < 16; ++r) {
            const int row = crowb + m * 32 + (r & 3) + 8 * (r >> 2);
            ushort* dst = &Cb[(size_t)row * N_DIM + ccolb];
            dst[0]  = f2bf((float)acc[m][0][r] * sc0);
            dst[32] = f2bf((float)acc[m][1][r] * sc1);
        }
    }
#undef RD_A
#undef RD_B
}

// ---------------- Mobius epilogue: out = srow * Cb * gain(norm(srow*Cb)) ----------------
__global__ __launch_bounds__(256) void mobius_bf16(const ushort* __restrict__ Cb,
                                                   const float* __restrict__ srow,
                                                   float* __restrict__ out) {
    const int row = blockIdx.x;
    const ushort* p = Cb + (size_t)row * N_DIM;
    float* q = out + (size_t)row * N_DIM;
    const int t = threadIdx.x;
    const float s = srow[row];

    typedef __attribute__((ext_vector_type(8))) short short8;
    short8 v = *(const short8*)&p[t * 8];
    float f[8];
#pragma unroll
    for (int j = 0; j < 8; ++j) {
        const uint32_t u = ((uint32_t)(uint16_t)v[j]) << 16;
        f[j] = __builtin_bit_cast(float, u);
    }
    float ss = 0.f;
#pragma unroll
    for (int j = 0; j < 8; ++j) ss += f[j] * f[j];
#pragma unroll
    for (int off = 1; off < 64; off <<= 1) ss += __shfl_xor(ss, off);
    __shared__ float wsum[4];
    if ((t & 63) == 0) wsum[t >> 6] = ss;
    __syncthreads();
    const float tot = (wsum[0] + wsum[1] + wsum[2] + wsum[3]) * s * s;
    const float vn = fmaxf(sqrtf(tot), 1e-7f);
    const float tf = tanhf(vn) / (vn + 1e-7f);
    const float on = fmaxf(tf * vn, 1e-7f);
    const float g = s * tf * fminf(0.99f / on, 1.0f);
    float4v o0, o1;
#pragma unroll
    for (int j = 0; j < 4; ++j) { o0[j] = f[j] * g; o1[j] = f[4 + j] * g; }
    *(float4v*)&q[t * 8] = o0;
    *(float4v*)&q[t * 8 + 4] = o1;
}

extern "C" void kernel_launch(void* const* d_in, const int* in_sizes, int n_in,
                              void* d_out, int out_size, void* d_ws, size_t ws_size,
                              hipStream_t stream) {
    const float* x = (const float*)d_in[0];
    const float* w = (const float*)d_in[1];
    const float* scale = (const float*)d_in[2];
    float* out = (float*)d_out;

    // ws layout: Wq @0 (4 MB), Xq @4M (16 MB), srow @20971520 (32 KB), Cb @21037056 (32 MB)
    signed char* Wq = (signed char*)d_ws;
    signed char* Xq = (signed char*)d_ws + 4194304;
    float* srow = (float*)((char*)d_ws + 20971520);
    ushort* Cb = (ushort*)((char*)d_ws + 21037056);

    prep_kernel<<<dim3(4096 + 8192), dim3(256), 0, stream>>>(w, x, Wq, Xq, srow);
    gemm_i8<<<dim3((M_DIM / BM) * (N_DIM / BN)), dim3(512), 0, stream>>>(Xq, Wq, scale, Cb);
    mobius_bf16<<<dim3(M_DIM), dim3(256), 0, stream>>>(Cb, srow, out);
}